// Round 3
// baseline (665.754 us; speedup 1.0000x reference)
//
#include <hip/hip_runtime.h>
#include <hip/hip_bf16.h>

typedef __hip_bfloat16 bf16;
typedef __attribute__((ext_vector_type(8))) short short8;
typedef __attribute__((ext_vector_type(8))) unsigned short ushort8;
typedef __attribute__((ext_vector_type(4))) float floatx4;

__device__ __forceinline__ float us2f(unsigned short u) {
  unsigned int i = ((unsigned int)u) << 16;
  float f;
  __builtin_memcpy(&f, &i, 4);
  return f;
}
__device__ __forceinline__ short f2s(float x) {
  bf16 h = __float2bfloat16(x);
  short s;
  __builtin_memcpy(&s, &h, 2);
  return s;
}

// Runtime dtype probe: reads the first 128 16-bit words. All bf16 tensors in this
// problem have |value| < 100; fp32 tensors have uniform-random mantissa low-words,
// so at least one of 64 low-words decodes to |bf16| > 100 (or NaN) w.p. ~1-1e-18.
__device__ __forceinline__ int detect_f32(const void* p) {
  const ushort8* v = (const ushort8*)p;
  int big = 0;
  #pragma unroll
  for (int c = 0; c < 16; ++c) {
    ushort8 u = v[c];
    #pragma unroll
    for (int j = 0; j < 8; ++j) {
      float f = us2f(u[j]);
      if (!(__builtin_fabsf(f) <= 100.f)) big = 1;  // NaN fails <= -> caught
    }
  }
  return big;
}

// Load 8 consecutive elements (element index `idx`) as bf16 bits.
__device__ __forceinline__ short8 load8w(const void* base, int idx, int is32) {
  if (!is32) {
    return *(const short8*)((const unsigned short*)base + idx);
  }
  const float* f = (const float*)base + idx;
  float4 a = *(const float4*)f;
  float4 b = *(const float4*)(f + 4);
  short8 r;
  r[0] = f2s(a.x); r[1] = f2s(a.y); r[2] = f2s(a.z); r[3] = f2s(a.w);
  r[4] = f2s(b.x); r[5] = f2s(b.y); r[6] = f2s(b.z); r[7] = f2s(b.w);
  return r;
}

#define MFMA16(a, b, c) __builtin_amdgcn_mfma_f32_16x16x32_bf16((a), (b), (c), 0, 0, 0)

// C = A @ W^T (+bias). A: (rows x 1024), W: (1024 x 1024) row-major; dtypes runtime-probed.
// QKV mode (grid.y=24): bf16 out O0..O2 selected by blockIdx.y/8. Final mode (grid.y=8): fp32 Ofp.
__global__ __launch_bounds__(256) void gemm_bt(
    const void* __restrict__ A, int aExt, int aOff,
    const void* __restrict__ W0, const void* __restrict__ W1, const void* __restrict__ W2,
    const void* __restrict__ bias, int hasBias,
    bf16* __restrict__ O0, bf16* __restrict__ O1, bf16* __restrict__ O2,
    float* __restrict__ Ofp, int outF32)
{
  __shared__ bf16 As[128 * 64];
  __shared__ bf16 Bs[128 * 64];

  const int m0 = blockIdx.x * 128;
  const int by = blockIdx.y;
  const int which = by >> 3;
  const void* W = (which == 0) ? W0 : (which == 1) ? W1 : W2;
  bf16* O = (which == 0) ? O0 : (which == 1) ? O1 : O2;
  const int n0 = (by & 7) * 128;

  const int t = threadIdx.x;
  const int lane = t & 63, w = t >> 6;
  const int lrow = lane >> 3, lcol = (lane & 7) * 8;
  const int wm = w >> 1, wn = w & 1;
  const int quad = lane >> 4, n16 = lane & 15;

  const int a32 = aExt ? detect_f32(A) : 0;
  const int w32 = detect_f32(W);

  floatx4 acc[4][4];
  const floatx4 zero4 = {0.f, 0.f, 0.f, 0.f};
  #pragma unroll
  for (int mi = 0; mi < 4; ++mi)
    #pragma unroll
    for (int ni = 0; ni < 4; ++ni) acc[mi][ni] = zero4;

  const int arowb = m0 + w * 32 + lrow;
  const int browb = n0 + w * 32 + lrow;
  bf16* la = As + w * 2048 + lane * 8;
  bf16* lb = Bs + w * 2048 + lane * 8;

  for (int k0 = 0; k0 < 1024; k0 += 64) {
    short8 ra[4], rb[4];
    #pragma unroll
    for (int c = 0; c < 4; ++c) {
      ra[c] = load8w(A, aOff + (arowb + c * 8) * 1024 + k0 + lcol, a32);
      rb[c] = load8w(W, (browb + c * 8) * 1024 + k0 + lcol, w32);
    }
    if (k0) __syncthreads();   // previous iteration's LDS readers done
    #pragma unroll
    for (int c = 0; c < 4; ++c) {
      *(short8*)(la + c * 512) = ra[c];
      *(short8*)(lb + c * 512) = rb[c];
    }
    __syncthreads();
    #pragma unroll
    for (int ks = 0; ks < 2; ++ks) {
      short8 af[4], bfv[4];
      #pragma unroll
      for (int mi = 0; mi < 4; ++mi)
        af[mi] = *(const short8*)(As + (wm * 64 + mi * 16 + n16) * 64 + ks * 32 + quad * 8);
      #pragma unroll
      for (int ni = 0; ni < 4; ++ni)
        bfv[ni] = *(const short8*)(Bs + (wn * 64 + ni * 16 + n16) * 64 + ks * 32 + quad * 8);
      #pragma unroll
      for (int mi = 0; mi < 4; ++mi)
        #pragma unroll
        for (int ni = 0; ni < 4; ++ni)
          acc[mi][ni] = MFMA16(af[mi], bfv[ni], acc[mi][ni]);
    }
  }

  #pragma unroll
  for (int ni = 0; ni < 4; ++ni) {
    const int col = n0 + wn * 64 + ni * 16 + n16;
    float bv = 0.f;
    if (hasBias)  // bias dtype follows the weights' flag (bias may be all-zero: unprobeable)
      bv = w32 ? ((const float*)bias)[col] : us2f(((const unsigned short*)bias)[col]);
    #pragma unroll
    for (int mi = 0; mi < 4; ++mi) {
      #pragma unroll
      for (int r = 0; r < 4; ++r) {
        const int row = m0 + wm * 64 + mi * 16 + quad * 4 + r;
        if (outF32) Ofp[row * 1024 + col] = acc[mi][ni][r] + bv;
        else        O[row * 1024 + col] = __float2bfloat16(acc[mi][ni][r] + bv);
      }
    }
  }
}

// One block per (b_local, h). Q/K/V/Ctx are internal bf16; e-tables runtime-probed.
__global__ __launch_bounds__(256) void attn_rel(
    const bf16* __restrict__ Q, const bf16* __restrict__ Km, const bf16* __restrict__ V,
    const void* __restrict__ eqh, const void* __restrict__ eqw,
    const void* __restrict__ ekh, const void* __restrict__ ekw,
    const void* __restrict__ evh, const void* __restrict__ evw,
    bf16* __restrict__ Ctx)
{
  __shared__ bf16 qs[64][72];
  __shared__ bf16 ks[64][72];
  __shared__ bf16 vT[64][104];      // vT[d][k]: k<64 v[j=k][d]; 64..78 ev_h; 79..93 ev_w; 94,95 zero
  __shared__ bf16 pa[64][104];      // attn_aug[i][k]: k<64 attn; 64..78 P_h; 79..93 P_w; 94,95 zero
  __shared__ bf16 et2[15][392];     // et2[r][tbl*64+d], tbl: eqh,eqw,ekh,ekw,evh,evw
  __shared__ float Ah[64][16], Aw[64][16];
  __shared__ float Bh[15][64], Bw[15][64];
  __shared__ float S4[15][15];

  const int t = threadIdx.x;
  const int b = blockIdx.x >> 4, h = blockIdx.x & 15;
  const int base = b * 65536 + h * 64;

  // ---------- phase 1a: stage q, k, transposed v; zero pads ----------
  {
    const int r = t >> 2, c0 = (t & 3) * 16;
    const int off = base + r * 1024 + c0;
    int4 q0 = *(const int4*)(Q + off);
    int4 q1 = *(const int4*)(Q + off + 8);
    int4 k0 = *(const int4*)(Km + off);
    int4 k1 = *(const int4*)(Km + off + 8);
    *(int4*)&qs[r][c0] = q0; *(int4*)&qs[r][c0 + 8] = q1;
    *(int4*)&ks[r][c0] = k0; *(int4*)&ks[r][c0 + 8] = k1;
    int4 v0 = *(const int4*)(V + off);
    int4 v1 = *(const int4*)(V + off + 8);
    const unsigned short* p0 = (const unsigned short*)&v0;
    const unsigned short* p1 = (const unsigned short*)&v1;
    #pragma unroll
    for (int ii = 0; ii < 8; ++ii) {
      *(unsigned short*)&vT[c0 + ii][r] = p0[ii];
      *(unsigned short*)&vT[c0 + 8 + ii][r] = p1[ii];
    }
    if (t < 64) {
      *(unsigned short*)&vT[t][94] = 0; *(unsigned short*)&vT[t][95] = 0;
      *(unsigned short*)&pa[t][94] = 0; *(unsigned short*)&pa[t][95] = 0;
    }
  }
  // ---------- phase 1b: stage e-tables to LDS (dtype-probed) ----------
  {
    const int e32 = detect_f32(eqh);
    if (t < 120) {
      const void* eptr[6] = {eqh, eqw, ekh, ekw, evh, evw};
      const int r = t >> 3, d = (t & 7) * 8;
      #pragma unroll
      for (int tb = 0; tb < 6; ++tb) {
        short8 vv = load8w(eptr[tb], t * 8, e32);
        *(short8*)&et2[r][tb * 64 + d] = vv;
      }
    }
  }
  __syncthreads();

  // ---------- phase 2a: augment vT with ev_h / ev_w ----------
  if (t < 60) {
    const int r2 = t >> 2, c0 = (t & 3) * 16;
    ushort8 pe0 = *(const ushort8*)&et2[r2][256 + c0];
    ushort8 pe1 = *(const ushort8*)&et2[r2][256 + c0 + 8];
    ushort8 pf0 = *(const ushort8*)&et2[r2][320 + c0];
    ushort8 pf1 = *(const ushort8*)&et2[r2][320 + c0 + 8];
    #pragma unroll
    for (int ii = 0; ii < 8; ++ii) {
      *(unsigned short*)&vT[c0 + ii][64 + r2] = pe0[ii];
      *(unsigned short*)&vT[c0 + 8 + ii][64 + r2] = pe1[ii];
      *(unsigned short*)&vT[c0 + ii][79 + r2] = pf0[ii];
      *(unsigned short*)&vT[c0 + 8 + ii][79 + r2] = pf1[ii];
    }
  }
  // ---------- phase 2b: relative-score tables ----------
  #pragma unroll
  for (int kk = 0; kk < 4; ++kk) {
    const int idx = t + 256 * kk;
    if (idx < 960) {
      const int i = idx & 63, r = idx >> 6;
      float s1 = 0.f, s2 = 0.f, s3 = 0.f, s4v = 0.f;
      #pragma unroll
      for (int c8 = 0; c8 < 8; ++c8) {
        ushort8 qv = *(const ushort8*)&qs[i][c8 * 8];
        ushort8 kv = *(const ushort8*)&ks[i][c8 * 8];
        ushort8 e1 = *(const ushort8*)&et2[r][128 + c8 * 8];  // ekh
        ushort8 e2 = *(const ushort8*)&et2[r][192 + c8 * 8];  // ekw
        ushort8 e3 = *(const ushort8*)&et2[r][0 + c8 * 8];    // eqh
        ushort8 e4 = *(const ushort8*)&et2[r][64 + c8 * 8];   // eqw
        #pragma unroll
        for (int jj = 0; jj < 8; ++jj) {
          const float qf = us2f(qv[jj]), kf = us2f(kv[jj]);
          s1 += qf * us2f(e1[jj]);
          s2 += qf * us2f(e2[jj]);
          s3 += kf * us2f(e3[jj]);
          s4v += kf * us2f(e4[jj]);
        }
      }
      Ah[i][r] = s1; Aw[i][r] = s2; Bh[r][i] = s3; Bw[r][i] = s4v;
    }
  }
  if (t < 225) {
    const int r = t / 15, c = t % 15;
    float s = 0.f;
    #pragma unroll
    for (int c8 = 0; c8 < 8; ++c8) {
      ushort8 a1 = *(const ushort8*)&et2[r][0 + c8 * 8];     // eqh[r]
      ushort8 a2 = *(const ushort8*)&et2[c][64 + c8 * 8];    // eqw[c]
      ushort8 b1 = *(const ushort8*)&et2[r][128 + c8 * 8];   // ekh[r]
      ushort8 b2 = *(const ushort8*)&et2[c][192 + c8 * 8];   // ekw[c]
      #pragma unroll
      for (int jj = 0; jj < 8; ++jj)
        s += (us2f(a1[jj]) + us2f(a2[jj])) * (us2f(b1[jj]) + us2f(b2[jj]));
    }
    S4[r][c] = s;
  }
  __syncthreads();

  // ---------- phase 3: scores MFMA + rel add + softmax ----------
  const int lane = t & 63, w = t >> 6;
  const int quad = lane >> 4, n16 = lane & 15;
  const int i_base = w * 16 + quad * 4;

  short8 aq0 = *(const short8*)&qs[w * 16 + n16][quad * 8];
  short8 aq1 = *(const short8*)&qs[w * 16 + n16][32 + quad * 8];
  float xv[4][4];
  #pragma unroll
  for (int nj = 0; nj < 4; ++nj) {
    short8 bk0 = *(const short8*)&ks[nj * 16 + n16][quad * 8];
    short8 bk1 = *(const short8*)&ks[nj * 16 + n16][32 + quad * 8];
    floatx4 c = {0.f, 0.f, 0.f, 0.f};
    c = MFMA16(aq0, bk0, c);
    c = MFMA16(aq1, bk1, c);
    const int j = nj * 16 + n16;
    const int rowj = j >> 3, colj = j & 7;
    #pragma unroll
    for (int r = 0; r < 4; ++r) {
      const int i = i_base + r;
      const int rowi = i >> 3, coli = i & 7;
      const int rr = rowi - rowj + 7, rc = coli - colj + 7;
      xv[r][nj] = (c[r] + Ah[i][rr] + Aw[i][rc] + Bh[rr][j] + Bw[rc][j] + S4[rr][rc]) * 0.125f;
    }
  }
  #pragma unroll
  for (int r = 0; r < 4; ++r) {
    float mx = fmaxf(fmaxf(xv[r][0], xv[r][1]), fmaxf(xv[r][2], xv[r][3]));
    #pragma unroll
    for (int off = 1; off < 16; off <<= 1) mx = fmaxf(mx, __shfl_xor(mx, off));
    const float e0 = __expf(xv[r][0] - mx), e1 = __expf(xv[r][1] - mx),
                e2 = __expf(xv[r][2] - mx), e3 = __expf(xv[r][3] - mx);
    float sm = e0 + e1 + e2 + e3;
    #pragma unroll
    for (int off = 1; off < 16; off <<= 1) sm += __shfl_xor(sm, off);
    const float inv = 1.0f / sm;
    const int i = i_base + r;
    pa[i][0 + n16]  = __float2bfloat16(e0 * inv);
    pa[i][16 + n16] = __float2bfloat16(e1 * inv);
    pa[i][32 + n16] = __float2bfloat16(e2 * inv);
    pa[i][48 + n16] = __float2bfloat16(e3 * inv);
  }
  __syncthreads();

  // ---------- phase 4: bin attn into P_h / P_w (cols 64..93 of pa) ----------
  #pragma unroll
  for (int kk = 0; kk < 4; ++kk) {
    const int idx = t + 256 * kk;
    if (idx < 960) {
      const int i = idx & 63, r = idx >> 6;
      const int rowi = i >> 3, coli = i & 7;
      const int rowj = rowi + 7 - r;
      float s = 0.f;
      if (rowj >= 0 && rowj < 8) {
        #pragma unroll
        for (int cj = 0; cj < 8; ++cj) s += __bfloat162float(pa[i][rowj * 8 + cj]);
      }
      pa[i][64 + r] = __float2bfloat16(s);
      const int colj = coli + 7 - r;
      float s2 = 0.f;
      if (colj >= 0 && colj < 8) {
        #pragma unroll
        for (int rj = 0; rj < 8; ++rj) s2 += __bfloat162float(pa[i][rj * 8 + colj]);
      }
      pa[i][79 + r] = __float2bfloat16(s2);
    }
  }
  __syncthreads();

  // ---------- phase 5: ctx = attn_aug (64x96) @ Vaug (96x64) ----------
  short8 ap[3];
  #pragma unroll
  for (int ksb = 0; ksb < 3; ++ksb)
    ap[ksb] = *(const short8*)&pa[w * 16 + n16][ksb * 32 + quad * 8];
  #pragma unroll
  for (int nj = 0; nj < 4; ++nj) {
    floatx4 c = {0.f, 0.f, 0.f, 0.f};
    #pragma unroll
    for (int ksb = 0; ksb < 3; ++ksb) {
      short8 bv = *(const short8*)&vT[nj * 16 + n16][ksb * 32 + quad * 8];
      c = MFMA16(ap[ksb], bv, c);
    }
    #pragma unroll
    for (int r = 0; r < 4; ++r) {
      const int i = i_base + r;
      Ctx[base + i * 1024 + nj * 16 + n16] = __float2bfloat16(c[r]);
    }
  }
}

extern "C" void kernel_launch(void* const* d_in, const int* in_sizes, int n_in,
                              void* d_out, int out_size, void* d_ws, size_t ws_size,
                              hipStream_t stream) {
  const void* x   = d_in[0];
  const void* wq  = d_in[1];
  const void* wk  = d_in[2];
  const void* wv  = d_in[3];
  const void* wo  = d_in[4];
  const void* bo  = d_in[5];
  const void* eqh = d_in[6];
  const void* eqw = d_in[7];
  const void* ekh = d_in[8];
  const void* ekw = d_in[9];
  const void* evh = d_in[10];
  const void* evw = d_in[11];

  // Output committed as fp32 (reference returns float32). out buffer = 64 MB.
  float* outf = (float*)d_out;
  // ws: only 32 MB used (q, k for one half-batch). ctx overwrites q in place.
  bf16* qb = (bf16*)d_ws;
  bf16* kb = qb + 8388608;
  // v per half parked in out's upper 32 MB (bytes [32,48) MB and [48,64) MB);
  // consumed by attn before the final GEMM of half B overwrites those bytes.
  bf16* vA = (bf16*)((char*)d_out + 33554432);
  bf16* vB = (bf16*)((char*)d_out + 50331648);

  for (int hh = 0; hh < 2; ++hh) {
    bf16* vh = hh ? vB : vA;
    // fused QKV projection for this half: x_half @ {wq,wk,wv}^T
    gemm_bt<<<dim3(64, 24), 256, 0, stream>>>(
        x, 1, hh * 8388608, wq, wk, wv, nullptr, 0, qb, kb, vh, nullptr, 0);
    // relative attention per (b_local, h); ctx overwrites qb (disjoint per block)
    attn_rel<<<dim3(2048), 256, 0, stream>>>(
        qb, kb, vh, eqh, eqw, ekh, ekw, evh, evw, qb);
    // output projection: ctx @ wo^T + bo -> fp32 out half
    gemm_bt<<<dim3(64, 8), 256, 0, stream>>>(
        qb, 0, 0, wo, nullptr, nullptr, bo, 1, nullptr, nullptr, nullptr,
        outf + (size_t)hh * 8388608, 1);
  }
}

// Round 4
// 478.134 us; speedup vs baseline: 1.3924x; 1.3924x over previous
//
#include <hip/hip_runtime.h>
#include <hip/hip_bf16.h>

typedef __hip_bfloat16 bf16;
typedef __attribute__((ext_vector_type(8))) short short8;
typedef __attribute__((ext_vector_type(8))) unsigned short ushort8;
typedef __attribute__((ext_vector_type(4))) float floatx4;

__device__ __forceinline__ float us2f(unsigned short u) {
  unsigned int i = ((unsigned int)u) << 16;
  float f;
  __builtin_memcpy(&f, &i, 4);
  return f;
}
__device__ __forceinline__ short f2s(float x) {
  bf16 h = __float2bfloat16(x);
  short s;
  __builtin_memcpy(&s, &h, 2);
  return s;
}

__device__ __forceinline__ void gl_lds16(const bf16* g, bf16* l) {
  __builtin_amdgcn_global_load_lds(
      (const __attribute__((address_space(1))) unsigned int*)g,
      (__attribute__((address_space(3))) unsigned int*)l, 16, 0, 0);
}

// Runtime dtype probe (used only by attn for the e-tables; GEMM dtypes are fixed).
__device__ __forceinline__ int detect_f32(const void* p) {
  const ushort8* v = (const ushort8*)p;
  int big = 0;
  #pragma unroll
  for (int c = 0; c < 16; ++c) {
    ushort8 u = v[c];
    #pragma unroll
    for (int j = 0; j < 8; ++j) {
      float f = us2f(u[j]);
      if (!(__builtin_fabsf(f) <= 100.f)) big = 1;
    }
  }
  return big;
}

__device__ __forceinline__ short8 load8w(const void* base, int idx, int is32) {
  if (!is32) {
    return *(const short8*)((const unsigned short*)base + idx);
  }
  const float* f = (const float*)base + idx;
  float4 a = *(const float4*)f;
  float4 b = *(const float4*)(f + 4);
  short8 r;
  r[0] = f2s(a.x); r[1] = f2s(a.y); r[2] = f2s(a.z); r[3] = f2s(a.w);
  r[4] = f2s(b.x); r[5] = f2s(b.y); r[6] = f2s(b.z); r[7] = f2s(b.w);
  return r;
}

#define MFMA16(a, b, c) __builtin_amdgcn_mfma_f32_16x16x32_bf16((a), (b), (c), 0, 0, 0)

// fp32 -> bf16 elementwise convert; each thread handles 8 elements.
__global__ __launch_bounds__(256) void convert_f32_bf16(
    const float* __restrict__ src, bf16* __restrict__ dst, int n) {
  const int i = (blockIdx.x * 256 + threadIdx.x) * 8;
  if (i + 7 < n) {
    float4 a = *(const float4*)(src + i);
    float4 b = *(const float4*)(src + i + 4);
    short8 r;
    r[0] = f2s(a.x); r[1] = f2s(a.y); r[2] = f2s(a.z); r[3] = f2s(a.w);
    r[4] = f2s(b.x); r[5] = f2s(b.y); r[6] = f2s(b.z); r[7] = f2s(b.w);
    *(short8*)(dst + i) = r;
  }
}

// C = A @ W^T (+bias). A: (M x 1024) bf16 row-major. W row-major 1024x1024,
// bf16 (wBf=1, global_load_lds staging) or fp32 (wBf=0, register-convert staging).
// QKV mode (grid.y=24): bf16 out O0..O2 by blockIdx.y/8. Final mode (grid.y=8): fp32 Ofp + bias.
__global__ __launch_bounds__(256) void gemm_bt(
    const bf16* __restrict__ A,
    const void* __restrict__ W0, const void* __restrict__ W1, const void* __restrict__ W2,
    int wBf,
    const float* __restrict__ bias, int hasBias,
    bf16* __restrict__ O0, bf16* __restrict__ O1, bf16* __restrict__ O2,
    float* __restrict__ Ofp, int outF32)
{
  __shared__ bf16 As[128 * 64];
  __shared__ bf16 Bs[128 * 64];

  const int m0 = blockIdx.x * 128;
  const int by = blockIdx.y;
  const int which = by >> 3;
  const void* W = (which == 0) ? W0 : (which == 1) ? W1 : W2;
  bf16* O = (which == 0) ? O0 : (which == 1) ? O1 : O2;
  const int n0 = (by & 7) * 128;

  const int t = threadIdx.x;
  const int lane = t & 63, w = t >> 6;
  const int lrow = lane >> 3, lcol = (lane & 7) * 8;
  const int wm = w >> 1, wn = w & 1;
  const int quad = lane >> 4, n16 = lane & 15;

  floatx4 acc[4][4];
  const floatx4 zero4 = {0.f, 0.f, 0.f, 0.f};
  #pragma unroll
  for (int mi = 0; mi < 4; ++mi)
    #pragma unroll
    for (int ni = 0; ni < 4; ++ni) acc[mi][ni] = zero4;

  const int arowb = m0 + w * 32 + lrow;          // per-lane A row
  const int browb = n0 + w * 32 + lrow;          // per-lane W row
  bf16* lau = As + w * 2048;                     // wave-uniform LDS bases for gl_lds
  bf16* lbu = Bs + w * 2048;

  if (wBf) {
    const bf16* Wb = (const bf16*)W;
    for (int k0 = 0; k0 < 1024; k0 += 64) {
      if (k0) __syncthreads();                   // previous iteration's readers done
      const bf16* ga = A + arowb * 1024 + k0 + lcol;
      const bf16* gw = Wb + browb * 1024 + k0 + lcol;
      #pragma unroll
      for (int c = 0; c < 4; ++c) {
        gl_lds16(ga + c * 8192, lau + c * 512);
        gl_lds16(gw + c * 8192, lbu + c * 512);
      }
      __syncthreads();                           // drains vmcnt incl. LDS-DMA
      #pragma unroll
      for (int ks = 0; ks < 2; ++ks) {
        short8 af[4], bfv[4];
        #pragma unroll
        for (int mi = 0; mi < 4; ++mi)
          af[mi] = *(const short8*)(As + (wm * 64 + mi * 16 + n16) * 64 + ks * 32 + quad * 8);
        #pragma unroll
        for (int ni = 0; ni < 4; ++ni)
          bfv[ni] = *(const short8*)(Bs + (wn * 64 + ni * 16 + n16) * 64 + ks * 32 + quad * 8);
        #pragma unroll
        for (int mi = 0; mi < 4; ++mi)
          #pragma unroll
          for (int ni = 0; ni < 4; ++ni)
            acc[mi][ni] = MFMA16(af[mi], bfv[ni], acc[mi][ni]);
      }
    }
  } else {
    const float* Wf = (const float*)W;
    for (int k0 = 0; k0 < 1024; k0 += 64) {
      short8 rb[4];
      #pragma unroll
      for (int c = 0; c < 4; ++c) {
        const float* f = Wf + (browb + c * 8) * 1024 + k0 + lcol;
        float4 a = *(const float4*)f;
        float4 b = *(const float4*)(f + 4);
        short8 r;
        r[0] = f2s(a.x); r[1] = f2s(a.y); r[2] = f2s(a.z); r[3] = f2s(a.w);
        r[4] = f2s(b.x); r[5] = f2s(b.y); r[6] = f2s(b.z); r[7] = f2s(b.w);
        rb[c] = r;
      }
      if (k0) __syncthreads();
      const bf16* ga = A + arowb * 1024 + k0 + lcol;
      #pragma unroll
      for (int c = 0; c < 4; ++c) {
        gl_lds16(ga + c * 8192, lau + c * 512);
        *(short8*)(lbu + lane * 8 + c * 512) = rb[c];
      }
      __syncthreads();
      #pragma unroll
      for (int ks = 0; ks < 2; ++ks) {
        short8 af[4], bfv[4];
        #pragma unroll
        for (int mi = 0; mi < 4; ++mi)
          af[mi] = *(const short8*)(As + (wm * 64 + mi * 16 + n16) * 64 + ks * 32 + quad * 8);
        #pragma unroll
        for (int ni = 0; ni < 4; ++ni)
          bfv[ni] = *(const short8*)(Bs + (wn * 64 + ni * 16 + n16) * 64 + ks * 32 + quad * 8);
        #pragma unroll
        for (int mi = 0; mi < 4; ++mi)
          #pragma unroll
          for (int ni = 0; ni < 4; ++ni)
            acc[mi][ni] = MFMA16(af[mi], bfv[ni], acc[mi][ni]);
      }
    }
  }

  #pragma unroll
  for (int ni = 0; ni < 4; ++ni) {
    const int col = n0 + wn * 64 + ni * 16 + n16;
    const float bv = hasBias ? bias[col] : 0.f;
    #pragma unroll
    for (int mi = 0; mi < 4; ++mi) {
      #pragma unroll
      for (int r = 0; r < 4; ++r) {
        const int row = m0 + wm * 64 + mi * 16 + quad * 4 + r;
        if (outF32) Ofp[row * 1024 + col] = acc[mi][ni][r] + bv;
        else        O[row * 1024 + col] = __float2bfloat16(acc[mi][ni][r] + bv);
      }
    }
  }
}

// One block per (b_local, h). Q/K/V/Ctx internal bf16; e-tables runtime-probed.
__global__ __launch_bounds__(256) void attn_rel(
    const bf16* __restrict__ Q, const bf16* __restrict__ Km, const bf16* __restrict__ V,
    const void* __restrict__ eqh, const void* __restrict__ eqw,
    const void* __restrict__ ekh, const void* __restrict__ ekw,
    const void* __restrict__ evh, const void* __restrict__ evw,
    bf16* __restrict__ Ctx)
{
  __shared__ bf16 qs[64][72];
  __shared__ bf16 ks[64][72];
  __shared__ bf16 vT[64][104];      // vT[d][k]: k<64 v[j=k][d]; 64..78 ev_h; 79..93 ev_w; 94,95 zero
  __shared__ bf16 pa[64][104];      // attn_aug[i][k]: k<64 attn; 64..78 P_h; 79..93 P_w; 94,95 zero
  __shared__ bf16 et2[15][392];     // et2[r][tbl*64+d], tbl: eqh,eqw,ekh,ekw,evh,evw
  __shared__ float Ah[64][16], Aw[64][16];
  __shared__ float Bh[15][64], Bw[15][64];
  __shared__ float S4[15][15];

  const int t = threadIdx.x;
  const int b = blockIdx.x >> 4, h = blockIdx.x & 15;
  const int base = b * 65536 + h * 64;

  // ---------- phase 1a: stage q, k, transposed v; zero pads ----------
  {
    const int r = t >> 2, c0 = (t & 3) * 16;
    const int off = base + r * 1024 + c0;
    int4 q0 = *(const int4*)(Q + off);
    int4 q1 = *(const int4*)(Q + off + 8);
    int4 k0 = *(const int4*)(Km + off);
    int4 k1 = *(const int4*)(Km + off + 8);
    *(int4*)&qs[r][c0] = q0; *(int4*)&qs[r][c0 + 8] = q1;
    *(int4*)&ks[r][c0] = k0; *(int4*)&ks[r][c0 + 8] = k1;
    int4 v0 = *(const int4*)(V + off);
    int4 v1 = *(const int4*)(V + off + 8);
    const unsigned short* p0 = (const unsigned short*)&v0;
    const unsigned short* p1 = (const unsigned short*)&v1;
    #pragma unroll
    for (int ii = 0; ii < 8; ++ii) {
      *(unsigned short*)&vT[c0 + ii][r] = p0[ii];
      *(unsigned short*)&vT[c0 + 8 + ii][r] = p1[ii];
    }
    if (t < 64) {
      *(unsigned short*)&vT[t][94] = 0; *(unsigned short*)&vT[t][95] = 0;
      *(unsigned short*)&pa[t][94] = 0; *(unsigned short*)&pa[t][95] = 0;
    }
  }
  // ---------- phase 1b: stage e-tables to LDS (dtype-probed) ----------
  {
    const int e32 = detect_f32(eqh);
    if (t < 120) {
      const void* eptr[6] = {eqh, eqw, ekh, ekw, evh, evw};
      const int r = t >> 3, d = (t & 7) * 8;
      #pragma unroll
      for (int tb = 0; tb < 6; ++tb) {
        short8 vv = load8w(eptr[tb], t * 8, e32);
        *(short8*)&et2[r][tb * 64 + d] = vv;
      }
    }
  }
  __syncthreads();

  // ---------- phase 2a: augment vT with ev_h / ev_w ----------
  if (t < 60) {
    const int r2 = t >> 2, c0 = (t & 3) * 16;
    ushort8 pe0 = *(const ushort8*)&et2[r2][256 + c0];
    ushort8 pe1 = *(const ushort8*)&et2[r2][256 + c0 + 8];
    ushort8 pf0 = *(const ushort8*)&et2[r2][320 + c0];
    ushort8 pf1 = *(const ushort8*)&et2[r2][320 + c0 + 8];
    #pragma unroll
    for (int ii = 0; ii < 8; ++ii) {
      *(unsigned short*)&vT[c0 + ii][64 + r2] = pe0[ii];
      *(unsigned short*)&vT[c0 + 8 + ii][64 + r2] = pe1[ii];
      *(unsigned short*)&vT[c0 + ii][79 + r2] = pf0[ii];
      *(unsigned short*)&vT[c0 + 8 + ii][79 + r2] = pf1[ii];
    }
  }
  // ---------- phase 2b: relative-score tables ----------
  #pragma unroll
  for (int kk = 0; kk < 4; ++kk) {
    const int idx = t + 256 * kk;
    if (idx < 960) {
      const int i = idx & 63, r = idx >> 6;
      float s1 = 0.f, s2 = 0.f, s3 = 0.f, s4v = 0.f;
      #pragma unroll
      for (int c8 = 0; c8 < 8; ++c8) {
        ushort8 qv = *(const ushort8*)&qs[i][c8 * 8];
        ushort8 kv = *(const ushort8*)&ks[i][c8 * 8];
        ushort8 e1 = *(const ushort8*)&et2[r][128 + c8 * 8];  // ekh
        ushort8 e2 = *(const ushort8*)&et2[r][192 + c8 * 8];  // ekw
        ushort8 e3 = *(const ushort8*)&et2[r][0 + c8 * 8];    // eqh
        ushort8 e4 = *(const ushort8*)&et2[r][64 + c8 * 8];   // eqw
        #pragma unroll
        for (int jj = 0; jj < 8; ++jj) {
          const float qf = us2f(qv[jj]), kf = us2f(kv[jj]);
          s1 += qf * us2f(e1[jj]);
          s2 += qf * us2f(e2[jj]);
          s3 += kf * us2f(e3[jj]);
          s4v += kf * us2f(e4[jj]);
        }
      }
      Ah[i][r] = s1; Aw[i][r] = s2; Bh[r][i] = s3; Bw[r][i] = s4v;
    }
  }
  if (t < 225) {
    const int r = t / 15, c = t % 15;
    float s = 0.f;
    #pragma unroll
    for (int c8 = 0; c8 < 8; ++c8) {
      ushort8 a1 = *(const ushort8*)&et2[r][0 + c8 * 8];
      ushort8 a2 = *(const ushort8*)&et2[c][64 + c8 * 8];
      ushort8 b1 = *(const ushort8*)&et2[r][128 + c8 * 8];
      ushort8 b2 = *(const ushort8*)&et2[c][192 + c8 * 8];
      #pragma unroll
      for (int jj = 0; jj < 8; ++jj)
        s += (us2f(a1[jj]) + us2f(a2[jj])) * (us2f(b1[jj]) + us2f(b2[jj]));
    }
    S4[r][c] = s;
  }
  __syncthreads();

  // ---------- phase 3: scores MFMA + rel add + softmax ----------
  const int lane = t & 63, w = t >> 6;
  const int quad = lane >> 4, n16 = lane & 15;
  const int i_base = w * 16 + quad * 4;

  short8 aq0 = *(const short8*)&qs[w * 16 + n16][quad * 8];
  short8 aq1 = *(const short8*)&qs[w * 16 + n16][32 + quad * 8];
  float xv[4][4];
  #pragma unroll
  for (int nj = 0; nj < 4; ++nj) {
    short8 bk0 = *(const short8*)&ks[nj * 16 + n16][quad * 8];
    short8 bk1 = *(const short8*)&ks[nj * 16 + n16][32 + quad * 8];
    floatx4 c = {0.f, 0.f, 0.f, 0.f};
    c = MFMA16(aq0, bk0, c);
    c = MFMA16(aq1, bk1, c);
    const int j = nj * 16 + n16;
    const int rowj = j >> 3, colj = j & 7;
    #pragma unroll
    for (int r = 0; r < 4; ++r) {
      const int i = i_base + r;
      const int rowi = i >> 3, coli = i & 7;
      const int rr = rowi - rowj + 7, rc = coli - colj + 7;
      xv[r][nj] = (c[r] + Ah[i][rr] + Aw[i][rc] + Bh[rr][j] + Bw[rc][j] + S4[rr][rc]) * 0.125f;
    }
  }
  #pragma unroll
  for (int r = 0; r < 4; ++r) {
    float mx = fmaxf(fmaxf(xv[r][0], xv[r][1]), fmaxf(xv[r][2], xv[r][3]));
    #pragma unroll
    for (int off = 1; off < 16; off <<= 1) mx = fmaxf(mx, __shfl_xor(mx, off));
    const float e0 = __expf(xv[r][0] - mx), e1 = __expf(xv[r][1] - mx),
                e2 = __expf(xv[r][2] - mx), e3 = __expf(xv[r][3] - mx);
    float sm = e0 + e1 + e2 + e3;
    #pragma unroll
    for (int off = 1; off < 16; off <<= 1) sm += __shfl_xor(sm, off);
    const float inv = 1.0f / sm;
    const int i = i_base + r;
    pa[i][0 + n16]  = __float2bfloat16(e0 * inv);
    pa[i][16 + n16] = __float2bfloat16(e1 * inv);
    pa[i][32 + n16] = __float2bfloat16(e2 * inv);
    pa[i][48 + n16] = __float2bfloat16(e3 * inv);
  }
  __syncthreads();

  // ---------- phase 4: bin attn into P_h / P_w (cols 64..93 of pa) ----------
  #pragma unroll
  for (int kk = 0; kk < 4; ++kk) {
    const int idx = t + 256 * kk;
    if (idx < 960) {
      const int i = idx & 63, r = idx >> 6;
      const int rowi = i >> 3, coli = i & 7;
      const int rowj = rowi + 7 - r;
      float s = 0.f;
      if (rowj >= 0 && rowj < 8) {
        #pragma unroll
        for (int cj = 0; cj < 8; ++cj) s += __bfloat162float(pa[i][rowj * 8 + cj]);
      }
      pa[i][64 + r] = __float2bfloat16(s);
      const int colj = coli + 7 - r;
      float s2 = 0.f;
      if (colj >= 0 && colj < 8) {
        #pragma unroll
        for (int rj = 0; rj < 8; ++rj) s2 += __bfloat162float(pa[i][rj * 8 + colj]);
      }
      pa[i][79 + r] = __float2bfloat16(s2);
    }
  }
  __syncthreads();

  // ---------- phase 5: ctx = attn_aug (64x96) @ Vaug (96x64) ----------
  short8 ap[3];
  #pragma unroll
  for (int ksb = 0; ksb < 3; ++ksb)
    ap[ksb] = *(const short8*)&pa[w * 16 + n16][ksb * 32 + quad * 8];
  #pragma unroll
  for (int nj = 0; nj < 4; ++nj) {
    floatx4 c = {0.f, 0.f, 0.f, 0.f};
    #pragma unroll
    for (int ksb = 0; ksb < 3; ++ksb) {
      short8 bv = *(const short8*)&vT[nj * 16 + n16][ksb * 32 + quad * 8];
      c = MFMA16(ap[ksb], bv, c);
    }
    #pragma unroll
    for (int r = 0; r < 4; ++r) {
      const int i = i_base + r;
      Ctx[base + i * 1024 + nj * 16 + n16] = __float2bfloat16(c[r]);
    }
  }
}

extern "C" void kernel_launch(void* const* d_in, const int* in_sizes, int n_in,
                              void* d_out, int out_size, void* d_ws, size_t ws_size,
                              hipStream_t stream) {
  const float* x   = (const float*)d_in[0];
  const float* wq  = (const float*)d_in[1];
  const float* wk  = (const float*)d_in[2];
  const float* wv  = (const float*)d_in[3];
  const float* wo  = (const float*)d_in[4];
  const float* bo  = (const float*)d_in[5];
  const void* eqh = d_in[6];
  const void* eqw = d_in[7];
  const void* ekh = d_in[8];
  const void* ekw = d_in[9];
  const void* evh = d_in[10];
  const void* evw = d_in[11];

  float* outf = (float*)d_out;
  // d_out (64 MB) quadrant plan: Q1=xb0, Q3=xb1 (dead before out-proj overwrites),
  // Q2=v for the current half (consumed by attn before out-proj half1 writes Q2).
  bf16* xb0 = (bf16*)((char*)d_out + 16777216);
  bf16* xb1 = (bf16*)((char*)d_out + 50331648);
  bf16* vQ2 = (bf16*)((char*)d_out + 33554432);
  // ws: qb (16 MB) + kb (16 MB); weights bf16 at +32 MB if ws allows.
  bf16* qb = (bf16*)d_ws;
  bf16* kb = qb + 8388608;
  const int fastW = (ws_size >= (size_t)42 * 1024 * 1024) ? 1 : 0;
  bf16* wqb = kb + 8388608;
  bf16* wkb = wqb + 1048576;
  bf16* wvb = wkb + 1048576;
  bf16* wob = wvb + 1048576;

  // prologue: convert x halves (and weights, if ws allows) to bf16
  convert_f32_bf16<<<4096, 256, 0, stream>>>(x, xb0, 8388608);
  convert_f32_bf16<<<4096, 256, 0, stream>>>(x + 8388608, xb1, 8388608);
  if (fastW) {
    convert_f32_bf16<<<512, 256, 0, stream>>>(wq, wqb, 1048576);
    convert_f32_bf16<<<512, 256, 0, stream>>>(wk, wkb, 1048576);
    convert_f32_bf16<<<512, 256, 0, stream>>>(wv, wvb, 1048576);
    convert_f32_bf16<<<512, 256, 0, stream>>>(wo, wob, 1048576);
  }

  for (int hh = 0; hh < 2; ++hh) {
    const bf16* xh = hh ? xb1 : xb0;
    // fused QKV projection: x_half @ {wq,wk,wv}^T
    gemm_bt<<<dim3(64, 24), 256, 0, stream>>>(
        xh,
        fastW ? (const void*)wqb : (const void*)wq,
        fastW ? (const void*)wkb : (const void*)wk,
        fastW ? (const void*)wvb : (const void*)wv,
        fastW, nullptr, 0, qb, kb, vQ2, nullptr, 0);
    // relative attention; ctx overwrites qb (disjoint per block)
    attn_rel<<<dim3(2048), 256, 0, stream>>>(
        qb, kb, vQ2, eqh, eqw, ekh, ekw, evh, evw, qb);
    // output projection: ctx @ wo^T + bo -> fp32 out half
    gemm_bt<<<dim3(64, 8), 256, 0, stream>>>(
        qb,
        fastW ? (const void*)wob : (const void*)wo, nullptr, nullptr,
        fastW, bo, 1, nullptr, nullptr, nullptr,
        outf + (size_t)hh * 8388608, 1);
  }
}

// Round 5
// 402.176 us; speedup vs baseline: 1.6554x; 1.1889x over previous
//
#include <hip/hip_runtime.h>
#include <hip/hip_bf16.h>

typedef __hip_bfloat16 bf16;
typedef __attribute__((ext_vector_type(8))) short short8;
typedef __attribute__((ext_vector_type(8))) unsigned short ushort8;
typedef __attribute__((ext_vector_type(4))) float floatx4;

__device__ __forceinline__ short f2s(float x) {
  bf16 h = __float2bfloat16(x);
  short s;
  __builtin_memcpy(&s, &h, 2);
  return s;
}

__device__ __forceinline__ void gl_lds16(const bf16* g, bf16* l) {
  __builtin_amdgcn_global_load_lds(
      (const __attribute__((address_space(1))) unsigned int*)g,
      (__attribute__((address_space(3))) unsigned int*)l, 16, 0, 0);
}

#define MFMA16(a, b, c) __builtin_amdgcn_mfma_f32_16x16x32_bf16((a), (b), (c), 0, 0, 0)

// fp32 -> bf16 elementwise convert; each thread handles 8 elements.
__global__ __launch_bounds__(256) void convert_f32_bf16(
    const float* __restrict__ src, bf16* __restrict__ dst, int n) {
  const int i = (blockIdx.x * 256 + threadIdx.x) * 8;
  if (i + 7 < n) {
    float4 a = *(const float4*)(src + i);
    float4 b = *(const float4*)(src + i + 4);
    short8 r;
    r[0] = f2s(a.x); r[1] = f2s(a.y); r[2] = f2s(a.z); r[3] = f2s(a.w);
    r[4] = f2s(b.x); r[5] = f2s(b.y); r[6] = f2s(b.z); r[7] = f2s(b.w);
    *(short8*)(dst + i) = r;
  }
}

// One-block precompute: bf16 e-tables (zero-padded to 16 rows each) + exact-fp32 S4.
// ews layout: [tbl][16][64], tbl order: eqh, eqw, ekh, ekw, evh, evw.
__global__ __launch_bounds__(256) void precompute_tables(
    const float* __restrict__ eqh, const float* __restrict__ eqw,
    const float* __restrict__ ekh, const float* __restrict__ ekw,
    const float* __restrict__ evh, const float* __restrict__ evw,
    bf16* __restrict__ ews, float* __restrict__ S4f)
{
  const int t = threadIdx.x;
  if (t < 96) {
    const int tb = t >> 4, row = t & 15;
    const float* src[6] = {eqh, eqw, ekh, ekw, evh, evw};
    bf16* dst = ews + tb * 1024 + row * 64;
    if (row < 15) {
      const float* s = src[tb] + row * 64;
      #pragma unroll
      for (int d = 0; d < 64; d += 8) {
        float4 a = *(const float4*)(s + d);
        float4 b2 = *(const float4*)(s + d + 4);
        short8 rr;
        rr[0] = f2s(a.x); rr[1] = f2s(a.y); rr[2] = f2s(a.z); rr[3] = f2s(a.w);
        rr[4] = f2s(b2.x); rr[5] = f2s(b2.y); rr[6] = f2s(b2.z); rr[7] = f2s(b2.w);
        *(short8*)(dst + d) = rr;
      }
    } else {
      const short8 z = {0, 0, 0, 0, 0, 0, 0, 0};
      #pragma unroll
      for (int d = 0; d < 64; d += 8) *(short8*)(dst + d) = z;
    }
  }
  if (t < 225) {
    const int r = t / 15, c = t % 15;
    float s = 0.f;
    for (int d = 0; d < 64; ++d)
      s += (eqh[r * 64 + d] + eqw[c * 64 + d]) * (ekh[r * 64 + d] + ekw[c * 64 + d]);
    S4f[t] = s;
  }
}

// C = A @ W^T (+bias). A: (M x 1024) bf16 row-major. W row-major 1024x1024,
// bf16 (wBf=1, global_load_lds staging) or fp32 (wBf=0, register-convert staging).
__global__ __launch_bounds__(256) void gemm_bt(
    const bf16* __restrict__ A,
    const void* __restrict__ W0, const void* __restrict__ W1, const void* __restrict__ W2,
    int wBf,
    const float* __restrict__ bias, int hasBias,
    bf16* __restrict__ O0, bf16* __restrict__ O1, bf16* __restrict__ O2,
    float* __restrict__ Ofp, int outF32)
{
  __shared__ bf16 As[128 * 64];
  __shared__ bf16 Bs[128 * 64];

  const int m0 = blockIdx.x * 128;
  const int by = blockIdx.y;
  const int which = by >> 3;
  const void* W = (which == 0) ? W0 : (which == 1) ? W1 : W2;
  bf16* O = (which == 0) ? O0 : (which == 1) ? O1 : O2;
  const int n0 = (by & 7) * 128;

  const int t = threadIdx.x;
  const int lane = t & 63, w = t >> 6;
  const int lrow = lane >> 3, lcol = (lane & 7) * 8;
  const int wm = w >> 1, wn = w & 1;
  const int quad = lane >> 4, n16 = lane & 15;

  floatx4 acc[4][4];
  const floatx4 zero4 = {0.f, 0.f, 0.f, 0.f};
  #pragma unroll
  for (int mi = 0; mi < 4; ++mi)
    #pragma unroll
    for (int ni = 0; ni < 4; ++ni) acc[mi][ni] = zero4;

  const int arowb = m0 + w * 32 + lrow;
  const int browb = n0 + w * 32 + lrow;
  bf16* lau = As + w * 2048;
  bf16* lbu = Bs + w * 2048;

  if (wBf) {
    const bf16* Wb = (const bf16*)W;
    for (int k0 = 0; k0 < 1024; k0 += 64) {
      if (k0) __syncthreads();
      const bf16* ga = A + arowb * 1024 + k0 + lcol;
      const bf16* gw = Wb + browb * 1024 + k0 + lcol;
      #pragma unroll
      for (int c = 0; c < 4; ++c) {
        gl_lds16(ga + c * 8192, lau + c * 512);
        gl_lds16(gw + c * 8192, lbu + c * 512);
      }
      __syncthreads();
      #pragma unroll
      for (int ks = 0; ks < 2; ++ks) {
        short8 af[4], bfv[4];
        #pragma unroll
        for (int mi = 0; mi < 4; ++mi)
          af[mi] = *(const short8*)(As + (wm * 64 + mi * 16 + n16) * 64 + ks * 32 + quad * 8);
        #pragma unroll
        for (int ni = 0; ni < 4; ++ni)
          bfv[ni] = *(const short8*)(Bs + (wn * 64 + ni * 16 + n16) * 64 + ks * 32 + quad * 8);
        #pragma unroll
        for (int mi = 0; mi < 4; ++mi)
          #pragma unroll
          for (int ni = 0; ni < 4; ++ni)
            acc[mi][ni] = MFMA16(af[mi], bfv[ni], acc[mi][ni]);
      }
    }
  } else {
    const float* Wf = (const float*)W;
    for (int k0 = 0; k0 < 1024; k0 += 64) {
      short8 rb[4];
      #pragma unroll
      for (int c = 0; c < 4; ++c) {
        const float* f = Wf + (browb + c * 8) * 1024 + k0 + lcol;
        float4 a = *(const float4*)f;
        float4 b = *(const float4*)(f + 4);
        short8 r;
        r[0] = f2s(a.x); r[1] = f2s(a.y); r[2] = f2s(a.z); r[3] = f2s(a.w);
        r[4] = f2s(b.x); r[5] = f2s(b.y); r[6] = f2s(b.z); r[7] = f2s(b.w);
        rb[c] = r;
      }
      if (k0) __syncthreads();
      const bf16* ga = A + arowb * 1024 + k0 + lcol;
      #pragma unroll
      for (int c = 0; c < 4; ++c) {
        gl_lds16(ga + c * 8192, lau + c * 512);
        *(short8*)(lbu + lane * 8 + c * 512) = rb[c];
      }
      __syncthreads();
      #pragma unroll
      for (int ks = 0; ks < 2; ++ks) {
        short8 af[4], bfv[4];
        #pragma unroll
        for (int mi = 0; mi < 4; ++mi)
          af[mi] = *(const short8*)(As + (wm * 64 + mi * 16 + n16) * 64 + ks * 32 + quad * 8);
        #pragma unroll
        for (int ni = 0; ni < 4; ++ni)
          bfv[ni] = *(const short8*)(Bs + (wn * 64 + ni * 16 + n16) * 64 + ks * 32 + quad * 8);
        #pragma unroll
        for (int mi = 0; mi < 4; ++mi)
          #pragma unroll
          for (int ni = 0; ni < 4; ++ni)
            acc[mi][ni] = MFMA16(af[mi], bfv[ni], acc[mi][ni]);
      }
    }
  }

  #pragma unroll
  for (int ni = 0; ni < 4; ++ni) {
    const int col = n0 + wn * 64 + ni * 16 + n16;
    const float bv = hasBias ? bias[col] : 0.f;
    #pragma unroll
    for (int mi = 0; mi < 4; ++mi) {
      #pragma unroll
      for (int r = 0; r < 4; ++r) {
        const int row = m0 + wm * 64 + mi * 16 + quad * 4 + r;
        if (outF32) Ofp[row * 1024 + col] = acc[mi][ni][r] + bv;
        else        O[row * 1024 + col] = __float2bfloat16(acc[mi][ni][r] + bv);
      }
    }
  }
}

// One block per (b_local, h). Rel tables via MFMA; binning in registers.
__global__ __launch_bounds__(256, 3) void attn_rel(
    const bf16* __restrict__ Q, const bf16* __restrict__ Km, const bf16* __restrict__ V,
    const bf16* __restrict__ ews, const float* __restrict__ S4f,
    bf16* __restrict__ Ctx)
{
  __shared__ bf16 vT[64][106];      // [d][k]: k<64 v[j=k][d]; 64..78 ev_h; 79..93 ev_w; 94,95 zero
  __shared__ bf16 pa[64][104];      // [i][k]: k<64 attn; 64..78 P_h; 79..93 P_w; 94,95 zero
  __shared__ float Ahs[64][16], Aws[64][16];   // q_i . ek_h[r] / ek_w[c]  (col 15 = 0)
  __shared__ float Bhs[15][64], Bws[15][64];   // eq_h[r] . k_j / eq_w[c] . k_j
  __shared__ float S4s[225];

  const int t = threadIdx.x;
  const int b = blockIdx.x >> 4, h = blockIdx.x & 15;
  const int base = b * 65536 + h * 64;
  const int lane = t & 63, w = t >> 6;
  const int quad = lane >> 4, n16 = lane & 15;

  // ---- phase 0: fragment loads straight from global ----
  const bf16* qrow = Q + base + (w * 16 + n16) * 1024 + quad * 8;
  short8 aq0 = *(const short8*)(qrow);
  short8 aq1 = *(const short8*)(qrow + 32);
  short8 bk0[4], bk1[4];
  #pragma unroll
  for (int nj = 0; nj < 4; ++nj) {
    const bf16* krow = Km + base + (nj * 16 + n16) * 1024 + quad * 8;
    bk0[nj] = *(const short8*)(krow);
    bk1[nj] = *(const short8*)(krow + 32);
  }
  short8 ebf[4][2];   // B-frags of eqh,eqw,ekh,ekw (row 15 zeroed by precompute)
  #pragma unroll
  for (int tb = 0; tb < 4; ++tb) {
    const bf16* er = ews + tb * 1024 + n16 * 64 + quad * 8;
    ebf[tb][0] = *(const short8*)(er);
    ebf[tb][1] = *(const short8*)(er + 32);
  }

  // ---- phase 1: stage transposed V + ev augmentation + S4; zero pads ----
  {
    const int r = t >> 2, c0 = (t & 3) * 16;
    const bf16* vrow = V + base + r * 1024 + c0;
    int4 v0 = *(const int4*)(vrow);
    int4 v1 = *(const int4*)(vrow + 8);
    const unsigned short* p0 = (const unsigned short*)&v0;
    const unsigned short* p1 = (const unsigned short*)&v1;
    #pragma unroll
    for (int ii = 0; ii < 8; ++ii) {
      *(unsigned short*)&vT[c0 + ii][r] = p0[ii];
      *(unsigned short*)&vT[c0 + 8 + ii][r] = p1[ii];
    }
    if (t < 60) {
      const int r2 = t >> 2, d0 = (t & 3) * 16;
      ushort8 pe0 = *(const ushort8*)(ews + 4096 + r2 * 64 + d0);
      ushort8 pe1 = *(const ushort8*)(ews + 4096 + r2 * 64 + d0 + 8);
      ushort8 pf0 = *(const ushort8*)(ews + 5120 + r2 * 64 + d0);
      ushort8 pf1 = *(const ushort8*)(ews + 5120 + r2 * 64 + d0 + 8);
      #pragma unroll
      for (int ii = 0; ii < 8; ++ii) {
        *(unsigned short*)&vT[d0 + ii][64 + r2] = pe0[ii];
        *(unsigned short*)&vT[d0 + 8 + ii][64 + r2] = pe1[ii];
        *(unsigned short*)&vT[d0 + ii][79 + r2] = pf0[ii];
        *(unsigned short*)&vT[d0 + 8 + ii][79 + r2] = pf1[ii];
      }
    }
    if (t < 64) {
      *(unsigned short*)&vT[t][94] = 0; *(unsigned short*)&vT[t][95] = 0;
      *(unsigned short*)&pa[t][94] = 0; *(unsigned short*)&pa[t][95] = 0;
    }
    if (t < 225) S4s[t] = S4f[t];
  }

  // ---- phase A: MFMAs — QK^T + rel tables; write tables to LDS ----
  floatx4 cqk[4];
  #pragma unroll
  for (int nj = 0; nj < 4; ++nj) {
    floatx4 c = {0.f, 0.f, 0.f, 0.f};
    c = MFMA16(aq0, bk0[nj], c);
    c = MFMA16(aq1, bk1[nj], c);
    cqk[nj] = c;
  }
  {
    floatx4 cah = {0.f, 0.f, 0.f, 0.f}, caw = cah, cbh = cah, cbw = cah;
    cah = MFMA16(aq0, ebf[2][0], cah); cah = MFMA16(aq1, ebf[2][1], cah);
    caw = MFMA16(aq0, ebf[3][0], caw); caw = MFMA16(aq1, ebf[3][1], caw);
    cbh = MFMA16(bk0[w], ebf[0][0], cbh); cbh = MFMA16(bk1[w], ebf[0][1], cbh);
    cbw = MFMA16(bk0[w], ebf[1][0], cbw); cbw = MFMA16(bk1[w], ebf[1][1], cbw);
    #pragma unroll
    for (int r = 0; r < 4; ++r) {
      const int i = w * 16 + quad * 4 + r;   // row i for Ah/Aw; key index j for Bh/Bw
      Ahs[i][n16] = cah[r];
      Aws[i][n16] = caw[r];
      if (n16 < 15) { Bhs[n16][i] = cbh[r]; Bws[n16][i] = cbw[r]; }
    }
  }
  __syncthreads();

  // ---- phase 3: rel add + softmax + register binning; write pa (wave-own rows) ----
  const int i_base = w * 16 + quad * 4;
  float xv[4][4];
  #pragma unroll
  for (int nj = 0; nj < 4; ++nj) {
    const int j = nj * 16 + n16;
    const int rowj = j >> 3, colj = j & 7;
    #pragma unroll
    for (int r = 0; r < 4; ++r) {
      const int i = i_base + r;
      const int rowi = i >> 3, coli = i & 7;
      const int rr = rowi - rowj + 7, rc = coli - colj + 7;
      xv[r][nj] = (cqk[nj][r] + Ahs[i][rr] + Aws[i][rc] + Bhs[rr][j] + Bws[rc][j]
                   + S4s[rr * 15 + rc]) * 0.125f;
    }
  }
  #pragma unroll
  for (int r = 0; r < 4; ++r) {
    const int i = i_base + r;
    const int rowi = i >> 3, coli = i & 7;
    float mx = fmaxf(fmaxf(xv[r][0], xv[r][1]), fmaxf(xv[r][2], xv[r][3]));
    #pragma unroll
    for (int off = 1; off < 16; off <<= 1) mx = fmaxf(mx, __shfl_xor(mx, off));
    float p[4];
    float sm = 0.f;
    #pragma unroll
    for (int nj = 0; nj < 4; ++nj) { p[nj] = __expf(xv[r][nj] - mx); sm += p[nj]; }
    #pragma unroll
    for (int off = 1; off < 16; off <<= 1) sm += __shfl_xor(sm, off);
    const float inv = 1.0f / sm;
    #pragma unroll
    for (int nj = 0; nj < 4; ++nj) {
      p[nj] *= inv;
      pa[i][nj * 16 + n16] = __float2bfloat16(p[nj]);
    }
    // P_h: butterfly over the 8 lanes sharing n16>>3 -> Ph'[i][g = nj*2 + (n16>>3)]
    float ph[4];
    #pragma unroll
    for (int nj = 0; nj < 4; ++nj) {
      float v = p[nj];
      v += __shfl_xor(v, 1); v += __shfl_xor(v, 2); v += __shfl_xor(v, 4);
      ph[nj] = v;
    }
    // P_w: Pw'[i][c = n16&7]
    float s4 = p[0] + p[1] + p[2] + p[3];
    float pw = s4 + __shfl_xor(s4, 8);
    if ((n16 & 7) == 0) {
      const int hh = n16 >> 3;
      #pragma unroll
      for (int nj = 0; nj < 4; ++nj) {
        const int g = nj * 2 + hh;
        pa[i][64 + rowi + 7 - g] = __float2bfloat16(ph[nj]);
      }
    } else if (n16 < 8) {
      const int z = n16 - 1;
      pa[i][64 + (z < rowi ? z : z + 8)] = __float2bfloat16(0.f);
    }
    if (n16 < 8) {
      pa[i][79 + coli + 7 - n16] = __float2bfloat16(pw);
    } else {
      const int z = n16 - 8;
      pa[i][79 + (z < coli ? z : z + 8)] = __float2bfloat16(0.f);  // z=7 hits zero-pad col 94
    }
  }
  __threadfence_block();   // pa writes -> same-wave pa reads below

  // ---- phase 5: ctx = attn_aug (64x96) @ Vaug (96x64) ----
  short8 ap[3];
  #pragma unroll
  for (int ksb = 0; ksb < 3; ++ksb)
    ap[ksb] = *(const short8*)&pa[w * 16 + n16][ksb * 32 + quad * 8];
  #pragma unroll
  for (int nj = 0; nj < 4; ++nj) {
    floatx4 c = {0.f, 0.f, 0.f, 0.f};
    #pragma unroll
    for (int ksb = 0; ksb < 3; ++ksb) {
      short8 bv = *(const short8*)&vT[nj * 16 + n16][ksb * 32 + quad * 8];
      c = MFMA16(ap[ksb], bv, c);
    }
    #pragma unroll
    for (int r = 0; r < 4; ++r) {
      const int i = i_base + r;
      Ctx[base + i * 1024 + nj * 16 + n16] = __float2bfloat16(c[r]);
    }
  }
}

extern "C" void kernel_launch(void* const* d_in, const int* in_sizes, int n_in,
                              void* d_out, int out_size, void* d_ws, size_t ws_size,
                              hipStream_t stream) {
  const float* x   = (const float*)d_in[0];
  const float* wq  = (const float*)d_in[1];
  const float* wk  = (const float*)d_in[2];
  const float* wv  = (const float*)d_in[3];
  const float* wo  = (const float*)d_in[4];
  const float* bo  = (const float*)d_in[5];
  const float* eqh = (const float*)d_in[6];
  const float* eqw = (const float*)d_in[7];
  const float* ekh = (const float*)d_in[8];
  const float* ekw = (const float*)d_in[9];
  const float* evh = (const float*)d_in[10];
  const float* evw = (const float*)d_in[11];
  float* outf = (float*)d_out;

  // 16KB table header at the tail of ws (clear of qb/kb/weights in all modes).
  const size_t hdr = (ws_size - 16384) & ~(size_t)1023;
  bf16* ewsB = (bf16*)((char*)d_ws + hdr);
  float* S4f = (float*)((char*)d_ws + hdr + 12288);
  precompute_tables<<<1, 256, 0, stream>>>(eqh, eqw, ekh, ekw, evh, evw, ewsB, S4f);

  if (ws_size >= (size_t)73 * 1024 * 1024) {
    // -------- full-batch path: ws = q(32M) | k(32M) | weights(8M) --------
    bf16* qb = (bf16*)d_ws;
    bf16* kb = qb + 16777216;
    bf16* wqb = kb + 16777216;
    bf16* wkb = wqb + 1048576;
    bf16* wvb = wkb + 1048576;
    bf16* wob = wvb + 1048576;
    bf16* xb = (bf16*)d_out;                      // d_out[0,32M): x bf16 (dead after QKV gemm)
    bf16* vb = (bf16*)((char*)d_out + 33554432);  // d_out[32M,64M): v (dead after attn)

    convert_f32_bf16<<<8192, 256, 0, stream>>>(x, xb, 16777216);
    convert_f32_bf16<<<512, 256, 0, stream>>>(wq, wqb, 1048576);
    convert_f32_bf16<<<512, 256, 0, stream>>>(wk, wkb, 1048576);
    convert_f32_bf16<<<512, 256, 0, stream>>>(wv, wvb, 1048576);
    convert_f32_bf16<<<512, 256, 0, stream>>>(wo, wob, 1048576);

    gemm_bt<<<dim3(128, 24), 256, 0, stream>>>(
        xb, wqb, wkb, wvb, 1, nullptr, 0, qb, kb, vb, nullptr, 0);
    attn_rel<<<dim3(4096), 256, 0, stream>>>(qb, kb, vb, ewsB, S4f, qb);
    gemm_bt<<<dim3(128, 8), 256, 0, stream>>>(
        qb, wob, nullptr, nullptr, 1, bo, 1, nullptr, nullptr, nullptr, outf, 1);
  } else {
    // -------- halved path (round-4 scheme) --------
    bf16* xb0 = (bf16*)((char*)d_out + 16777216);   // Q1
    bf16* xb1 = (bf16*)((char*)d_out + 50331648);   // Q3
    bf16* vQ2 = (bf16*)((char*)d_out + 33554432);   // Q2
    bf16* qb = (bf16*)d_ws;
    bf16* kb = qb + 8388608;
    const int fastW = (ws_size >= (size_t)42 * 1024 * 1024) ? 1 : 0;
    bf16* wqb = kb + 8388608;
    bf16* wkb = wqb + 1048576;
    bf16* wvb = wkb + 1048576;
    bf16* wob = wvb + 1048576;

    convert_f32_bf16<<<4096, 256, 0, stream>>>(x, xb0, 8388608);
    convert_f32_bf16<<<4096, 256, 0, stream>>>(x + 8388608, xb1, 8388608);
    if (fastW) {
      convert_f32_bf16<<<512, 256, 0, stream>>>(wq, wqb, 1048576);
      convert_f32_bf16<<<512, 256, 0, stream>>>(wk, wkb, 1048576);
      convert_f32_bf16<<<512, 256, 0, stream>>>(wv, wvb, 1048576);
      convert_f32_bf16<<<512, 256, 0, stream>>>(wo, wob, 1048576);
    }

    for (int hh = 0; hh < 2; ++hh) {
      const bf16* xh = hh ? xb1 : xb0;
      gemm_bt<<<dim3(64, 24), 256, 0, stream>>>(
          xh,
          fastW ? (const void*)wqb : (const void*)wq,
          fastW ? (const void*)wkb : (const void*)wk,
          fastW ? (const void*)wvb : (const void*)wv,
          fastW, nullptr, 0, qb, kb, vQ2, nullptr, 0);
      attn_rel<<<dim3(2048), 256, 0, stream>>>(qb, kb, vQ2, ewsB, S4f, qb);
      gemm_bt<<<dim3(64, 8), 256, 0, stream>>>(
          qb,
          fastW ? (const void*)wob : (const void*)wo, nullptr, nullptr,
          fastW, bo, 1, nullptr, nullptr, nullptr,
          outf + (size_t)hh * 8388608, 1);
    }
  }
}

// Round 6
// 378.055 us; speedup vs baseline: 1.7610x; 1.0638x over previous
//
#include <hip/hip_runtime.h>
#include <hip/hip_bf16.h>

typedef __hip_bfloat16 bf16;
typedef __attribute__((ext_vector_type(8))) short short8;
typedef __attribute__((ext_vector_type(8))) unsigned short ushort8;
typedef __attribute__((ext_vector_type(4))) float floatx4;

__device__ __forceinline__ short f2s(float x) {
  bf16 h = __float2bfloat16(x);
  short s;
  __builtin_memcpy(&s, &h, 2);
  return s;
}

__device__ __forceinline__ void gl_lds16(const bf16* g, bf16* l) {
  __builtin_amdgcn_global_load_lds(
      (const __attribute__((address_space(1))) unsigned int*)g,
      (__attribute__((address_space(3))) unsigned int*)l, 16, 0, 0);
}

#define MFMA16(a, b, c) __builtin_amdgcn_mfma_f32_16x16x32_bf16((a), (b), (c), 0, 0, 0)

// fp32 -> bf16 elementwise convert; each thread handles 8 elements.
__global__ __launch_bounds__(256) void convert_f32_bf16(
    const float* __restrict__ src, bf16* __restrict__ dst, int n) {
  const int i = (blockIdx.x * 256 + threadIdx.x) * 8;
  if (i + 7 < n) {
    float4 a = *(const float4*)(src + i);
    float4 b = *(const float4*)(src + i + 4);
    short8 r;
    r[0] = f2s(a.x); r[1] = f2s(a.y); r[2] = f2s(a.z); r[3] = f2s(a.w);
    r[4] = f2s(b.x); r[5] = f2s(b.y); r[6] = f2s(b.z); r[7] = f2s(b.w);
    *(short8*)(dst + i) = r;
  }
}

// One-block precompute: bf16 e-tables (zero-padded to 16 rows each) + exact-fp32 S4.
__global__ __launch_bounds__(256) void precompute_tables(
    const float* __restrict__ eqh, const float* __restrict__ eqw,
    const float* __restrict__ ekh, const float* __restrict__ ekw,
    const float* __restrict__ evh, const float* __restrict__ evw,
    bf16* __restrict__ ews, float* __restrict__ S4f)
{
  const int t = threadIdx.x;
  if (t < 96) {
    const int tb = t >> 4, row = t & 15;
    const float* src[6] = {eqh, eqw, ekh, ekw, evh, evw};
    bf16* dst = ews + tb * 1024 + row * 64;
    if (row < 15) {
      const float* s = src[tb] + row * 64;
      #pragma unroll
      for (int d = 0; d < 64; d += 8) {
        float4 a = *(const float4*)(s + d);
        float4 b2 = *(const float4*)(s + d + 4);
        short8 rr;
        rr[0] = f2s(a.x); rr[1] = f2s(a.y); rr[2] = f2s(a.z); rr[3] = f2s(a.w);
        rr[4] = f2s(b2.x); rr[5] = f2s(b2.y); rr[6] = f2s(b2.z); rr[7] = f2s(b2.w);
        *(short8*)(dst + d) = rr;
      }
    } else {
      const short8 z = {0, 0, 0, 0, 0, 0, 0, 0};
      #pragma unroll
      for (int d = 0; d < 64; d += 8) *(short8*)(dst + d) = z;
    }
  }
  if (t < 225) {
    const int r = t / 15, c = t % 15;
    float s = 0.f;
    for (int d = 0; d < 64; ++d)
      s += (eqh[r * 64 + d] + eqw[c * 64 + d]) * (ekh[r * 64 + d] + ekw[c * 64 + d]);
    S4f[t] = s;
  }
}

// C = A @ W^T (+bias). XOR-swizzled LDS (conflict-free fragment reads):
// LDS image element (row, c) holds global element (row, c ^ swz(row)),
// swz(r) = ((r&1)<<5) | (((r>>1)&3)<<3)  [elements; bits 3-5, disjoint from
// intra-fragment bits 0-2]. TAG distinguishes QKV vs out-proj in profiles.
template <int TAG>
__global__ __launch_bounds__(256) void gemm_bt(
    const bf16* __restrict__ A,
    const void* __restrict__ W0, const void* __restrict__ W1, const void* __restrict__ W2,
    int wBf,
    const float* __restrict__ bias, int hasBias,
    bf16* __restrict__ O0, bf16* __restrict__ O1, bf16* __restrict__ O2,
    float* __restrict__ Ofp, int outF32)
{
  __shared__ bf16 As[128 * 64];
  __shared__ bf16 Bs[128 * 64];

  const int m0 = blockIdx.x * 128;
  const int by = blockIdx.y;
  const int which = by >> 3;
  const void* W = (which == 0) ? W0 : (which == 1) ? W1 : W2;
  bf16* O = (which == 0) ? O0 : (which == 1) ? O1 : O2;
  const int n0 = (by & 7) * 128;

  const int t = threadIdx.x;
  const int lane = t & 63, w = t >> 6;
  const int lrow = lane >> 3, lcol = (lane & 7) * 8;
  const int wm = w >> 1, wn = w & 1;
  const int quad = lane >> 4, n16 = lane & 15;

  // source-column swizzle for the staging gather (row-parity + row-pair rotate)
  const int swzA = ((lrow & 1) << 5) | (((lrow >> 1) & 3) << 3);
  const int gcol = lcol ^ swzA;
  // fragment-read swizzle (row within 16-row tile == n16; bits 0-2 match lrow's)
  const int swzR = ((n16 & 1) << 5) | (((n16 >> 1) & 3) << 3);

  floatx4 acc[4][4];
  const floatx4 zero4 = {0.f, 0.f, 0.f, 0.f};
  #pragma unroll
  for (int mi = 0; mi < 4; ++mi)
    #pragma unroll
    for (int ni = 0; ni < 4; ++ni) acc[mi][ni] = zero4;

  const int arowb = m0 + w * 32 + lrow;
  const int browb = n0 + w * 32 + lrow;
  bf16* lau = As + w * 2048;
  bf16* lbu = Bs + w * 2048;

  if (wBf) {
    const bf16* Wb = (const bf16*)W;
    for (int k0 = 0; k0 < 1024; k0 += 64) {
      if (k0) __syncthreads();
      const bf16* ga = A + arowb * 1024 + k0 + gcol;
      const bf16* gw = Wb + browb * 1024 + k0 + gcol;
      #pragma unroll
      for (int c = 0; c < 4; ++c) {
        gl_lds16(ga + c * 8192, lau + c * 512);
        gl_lds16(gw + c * 8192, lbu + c * 512);
      }
      __syncthreads();
      #pragma unroll
      for (int ks = 0; ks < 2; ++ks) {
        short8 af[4], bfv[4];
        #pragma unroll
        for (int mi = 0; mi < 4; ++mi)
          af[mi] = *(const short8*)(As + (wm * 64 + mi * 16 + n16) * 64 +
                                    ((ks * 32 + quad * 8) ^ swzR));
        #pragma unroll
        for (int ni = 0; ni < 4; ++ni)
          bfv[ni] = *(const short8*)(Bs + (wn * 64 + ni * 16 + n16) * 64 +
                                     ((ks * 32 + quad * 8) ^ swzR));
        #pragma unroll
        for (int mi = 0; mi < 4; ++mi)
          #pragma unroll
          for (int ni = 0; ni < 4; ++ni)
            acc[mi][ni] = MFMA16(af[mi], bfv[ni], acc[mi][ni]);
      }
    }
  } else {
    const float* Wf = (const float*)W;
    for (int k0 = 0; k0 < 1024; k0 += 64) {
      short8 rb[4];
      #pragma unroll
      for (int c = 0; c < 4; ++c) {
        const float* f = Wf + (browb + c * 8) * 1024 + k0 + gcol;
        float4 a = *(const float4*)f;
        float4 b = *(const float4*)(f + 4);
        short8 r;
        r[0] = f2s(a.x); r[1] = f2s(a.y); r[2] = f2s(a.z); r[3] = f2s(a.w);
        r[4] = f2s(b.x); r[5] = f2s(b.y); r[6] = f2s(b.z); r[7] = f2s(b.w);
        rb[c] = r;
      }
      if (k0) __syncthreads();
      const bf16* ga = A + arowb * 1024 + k0 + gcol;
      #pragma unroll
      for (int c = 0; c < 4; ++c) {
        gl_lds16(ga + c * 8192, lau + c * 512);
        *(short8*)(lbu + lane * 8 + c * 512) = rb[c];
      }
      __syncthreads();
      #pragma unroll
      for (int ks = 0; ks < 2; ++ks) {
        short8 af[4], bfv[4];
        #pragma unroll
        for (int mi = 0; mi < 4; ++mi)
          af[mi] = *(const short8*)(As + (wm * 64 + mi * 16 + n16) * 64 +
                                    ((ks * 32 + quad * 8) ^ swzR));
        #pragma unroll
        for (int ni = 0; ni < 4; ++ni)
          bfv[ni] = *(const short8*)(Bs + (wn * 64 + ni * 16 + n16) * 64 +
                                     ((ks * 32 + quad * 8) ^ swzR));
        #pragma unroll
        for (int mi = 0; mi < 4; ++mi)
          #pragma unroll
          for (int ni = 0; ni < 4; ++ni)
            acc[mi][ni] = MFMA16(af[mi], bfv[ni], acc[mi][ni]);
      }
    }
  }

  #pragma unroll
  for (int ni = 0; ni < 4; ++ni) {
    const int col = n0 + wn * 64 + ni * 16 + n16;
    const float bv = hasBias ? bias[col] : 0.f;
    #pragma unroll
    for (int mi = 0; mi < 4; ++mi) {
      #pragma unroll
      for (int r = 0; r < 4; ++r) {
        const int row = m0 + wm * 64 + mi * 16 + quad * 4 + r;
        if (outF32) Ofp[row * 1024 + col] = acc[mi][ni][r] + bv;
        else        O[row * 1024 + col] = __float2bfloat16(acc[mi][ni][r] + bv);
      }
    }
  }
}

// One block per (b_local, h). Rel tables via MFMA; binning in registers.
__global__ __launch_bounds__(256, 3) void attn_rel(
    const bf16* __restrict__ Q, const bf16* __restrict__ Km, const bf16* __restrict__ V,
    const bf16* __restrict__ ews, const float* __restrict__ S4f,
    bf16* __restrict__ Ctx)
{
  __shared__ bf16 vT[64][106];      // [d][k]: k<64 v[j=k][d]; 64..78 ev_h; 79..93 ev_w; 94,95 zero
  __shared__ bf16 pa[64][104];      // [i][k]: k<64 attn; 64..78 P_h; 79..93 P_w; 94,95 zero
  __shared__ float Ahs[64][16], Aws[64][16];   // q_i . ek_h[r] / ek_w[c]  (col 15 = 0)
  __shared__ float Bhs[15][64], Bws[15][64];   // eq_h[r] . k_j / eq_w[c] . k_j
  __shared__ float S4s[225];

  const int t = threadIdx.x;
  const int b = blockIdx.x >> 4, h = blockIdx.x & 15;
  const int base = b * 65536 + h * 64;
  const int lane = t & 63, w = t >> 6;
  const int quad = lane >> 4, n16 = lane & 15;

  // ---- phase 0: fragment loads straight from global ----
  const bf16* qrow = Q + base + (w * 16 + n16) * 1024 + quad * 8;
  short8 aq0 = *(const short8*)(qrow);
  short8 aq1 = *(const short8*)(qrow + 32);
  short8 bk0[4], bk1[4];
  #pragma unroll
  for (int nj = 0; nj < 4; ++nj) {
    const bf16* krow = Km + base + (nj * 16 + n16) * 1024 + quad * 8;
    bk0[nj] = *(const short8*)(krow);
    bk1[nj] = *(const short8*)(krow + 32);
  }
  short8 ebf[4][2];   // B-frags of eqh,eqw,ekh,ekw (row 15 zeroed by precompute)
  #pragma unroll
  for (int tb = 0; tb < 4; ++tb) {
    const bf16* er = ews + tb * 1024 + n16 * 64 + quad * 8;
    ebf[tb][0] = *(const short8*)(er);
    ebf[tb][1] = *(const short8*)(er + 32);
  }

  // ---- phase 1: stage transposed V + ev augmentation + S4; zero pads ----
  {
    const int r = t >> 2, c0 = (t & 3) * 16;
    const bf16* vrow = V + base + r * 1024 + c0;
    int4 v0 = *(const int4*)(vrow);
    int4 v1 = *(const int4*)(vrow + 8);
    const unsigned short* p0 = (const unsigned short*)&v0;
    const unsigned short* p1 = (const unsigned short*)&v1;
    #pragma unroll
    for (int ii = 0; ii < 8; ++ii) {
      *(unsigned short*)&vT[c0 + ii][r] = p0[ii];
      *(unsigned short*)&vT[c0 + 8 + ii][r] = p1[ii];
    }
    if (t < 60) {
      const int r2 = t >> 2, d0 = (t & 3) * 16;
      ushort8 pe0 = *(const ushort8*)(ews + 4096 + r2 * 64 + d0);
      ushort8 pe1 = *(const ushort8*)(ews + 4096 + r2 * 64 + d0 + 8);
      ushort8 pf0 = *(const ushort8*)(ews + 5120 + r2 * 64 + d0);
      ushort8 pf1 = *(const ushort8*)(ews + 5120 + r2 * 64 + d0 + 8);
      #pragma unroll
      for (int ii = 0; ii < 8; ++ii) {
        *(unsigned short*)&vT[d0 + ii][64 + r2] = pe0[ii];
        *(unsigned short*)&vT[d0 + 8 + ii][64 + r2] = pe1[ii];
        *(unsigned short*)&vT[d0 + ii][79 + r2] = pf0[ii];
        *(unsigned short*)&vT[d0 + 8 + ii][79 + r2] = pf1[ii];
      }
    }
    if (t < 64) {
      *(unsigned short*)&vT[t][94] = 0; *(unsigned short*)&vT[t][95] = 0;
      *(unsigned short*)&pa[t][94] = 0; *(unsigned short*)&pa[t][95] = 0;
    }
    if (t < 225) S4s[t] = S4f[t];
  }

  // ---- phase A: MFMAs — QK^T + rel tables; write tables to LDS ----
  floatx4 cqk[4];
  #pragma unroll
  for (int nj = 0; nj < 4; ++nj) {
    floatx4 c = {0.f, 0.f, 0.f, 0.f};
    c = MFMA16(aq0, bk0[nj], c);
    c = MFMA16(aq1, bk1[nj], c);
    cqk[nj] = c;
  }
  {
    floatx4 cah = {0.f, 0.f, 0.f, 0.f}, caw = cah, cbh = cah, cbw = cah;
    cah = MFMA16(aq0, ebf[2][0], cah); cah = MFMA16(aq1, ebf[2][1], cah);
    caw = MFMA16(aq0, ebf[3][0], caw); caw = MFMA16(aq1, ebf[3][1], caw);
    cbh = MFMA16(bk0[w], ebf[0][0], cbh); cbh = MFMA16(bk1[w], ebf[0][1], cbh);
    cbw = MFMA16(bk0[w], ebf[1][0], cbw); cbw = MFMA16(bk1[w], ebf[1][1], cbw);
    #pragma unroll
    for (int r = 0; r < 4; ++r) {
      const int i = w * 16 + quad * 4 + r;   // row i for Ah/Aw; key index j for Bh/Bw
      Ahs[i][n16] = cah[r];
      Aws[i][n16] = caw[r];
      if (n16 < 15) { Bhs[n16][i] = cbh[r]; Bws[n16][i] = cbw[r]; }
    }
  }
  __syncthreads();

  // ---- phase 3: rel add + softmax + register binning; write pa (wave-own rows) ----
  const int i_base = w * 16 + quad * 4;
  float xv[4][4];
  #pragma unroll
  for (int nj = 0; nj < 4; ++nj) {
    const int j = nj * 16 + n16;
    const int rowj = j >> 3, colj = j & 7;
    #pragma unroll
    for (int r = 0; r < 4; ++r) {
      const int i = i_base + r;
      const int rowi = i >> 3, coli = i & 7;
      const int rr = rowi - rowj + 7, rc = coli - colj + 7;
      xv[r][nj] = (cqk[nj][r] + Ahs[i][rr] + Aws[i][rc] + Bhs[rr][j] + Bws[rc][j]
                   + S4s[rr * 15 + rc]) * 0.125f;
    }
  }
  #pragma unroll
  for (int r = 0; r < 4; ++r) {
    const int i = i_base + r;
    const int rowi = i >> 3, coli = i & 7;
    float mx = fmaxf(fmaxf(xv[r][0], xv[r][1]), fmaxf(xv[r][2], xv[r][3]));
    #pragma unroll
    for (int off = 1; off < 16; off <<= 1) mx = fmaxf(mx, __shfl_xor(mx, off));
    float p[4];
    float sm = 0.f;
    #pragma unroll
    for (int nj = 0; nj < 4; ++nj) { p[nj] = __expf(xv[r][nj] - mx); sm += p[nj]; }
    #pragma unroll
    for (int off = 1; off < 16; off <<= 1) sm += __shfl_xor(sm, off);
    const float inv = 1.0f / sm;
    #pragma unroll
    for (int nj = 0; nj < 4; ++nj) {
      p[nj] *= inv;
      pa[i][nj * 16 + n16] = __float2bfloat16(p[nj]);
    }
    // P_h: butterfly over the 8 lanes sharing n16>>3 -> Ph'[i][g = nj*2 + (n16>>3)]
    float ph[4];
    #pragma unroll
    for (int nj = 0; nj < 4; ++nj) {
      float v = p[nj];
      v += __shfl_xor(v, 1); v += __shfl_xor(v, 2); v += __shfl_xor(v, 4);
      ph[nj] = v;
    }
    // P_w: Pw'[i][c = n16&7]
    float s4 = p[0] + p[1] + p[2] + p[3];
    float pw = s4 + __shfl_xor(s4, 8);
    if ((n16 & 7) == 0) {
      const int hh = n16 >> 3;
      #pragma unroll
      for (int nj = 0; nj < 4; ++nj) {
        const int g = nj * 2 + hh;
        pa[i][64 + rowi + 7 - g] = __float2bfloat16(ph[nj]);
      }
    } else if (n16 < 8) {
      const int z = n16 - 1;
      pa[i][64 + (z < rowi ? z : z + 8)] = __float2bfloat16(0.f);
    }
    if (n16 < 8) {
      pa[i][79 + coli + 7 - n16] = __float2bfloat16(pw);
    } else {
      const int z = n16 - 8;
      pa[i][79 + (z < coli ? z : z + 8)] = __float2bfloat16(0.f);  // z=7 hits zero-pad col 94
    }
  }
  __threadfence_block();   // pa writes -> same-wave pa reads below

  // ---- phase 5: ctx = attn_aug (64x96) @ Vaug (96x64) ----
  short8 ap[3];
  #pragma unroll
  for (int ksb = 0; ksb < 3; ++ksb)
    ap[ksb] = *(const short8*)&pa[w * 16 + n16][ksb * 32 + quad * 8];
  #pragma unroll
  for (int nj = 0; nj < 4; ++nj) {
    floatx4 c = {0.f, 0.f, 0.f, 0.f};
    #pragma unroll
    for (int ksb = 0; ksb < 3; ++ksb) {
      short8 bv = *(const short8*)&vT[nj * 16 + n16][ksb * 32 + quad * 8];
      c = MFMA16(ap[ksb], bv, c);
    }
    #pragma unroll
    for (int r = 0; r < 4; ++r) {
      const int i = i_base + r;
      Ctx[base + i * 1024 + nj * 16 + n16] = __float2bfloat16(c[r]);
    }
  }
}

extern "C" void kernel_launch(void* const* d_in, const int* in_sizes, int n_in,
                              void* d_out, int out_size, void* d_ws, size_t ws_size,
                              hipStream_t stream) {
  const float* x   = (const float*)d_in[0];
  const float* wq  = (const float*)d_in[1];
  const float* wk  = (const float*)d_in[2];
  const float* wv  = (const float*)d_in[3];
  const float* wo  = (const float*)d_in[4];
  const float* bo  = (const float*)d_in[5];
  const float* eqh = (const float*)d_in[6];
  const float* eqw = (const float*)d_in[7];
  const float* ekh = (const float*)d_in[8];
  const float* ekw = (const float*)d_in[9];
  const float* evh = (const float*)d_in[10];
  const float* evw = (const float*)d_in[11];
  float* outf = (float*)d_out;

  // 16KB table header at the tail of ws (clear of qb/kb/weights in all modes).
  const size_t hdr = (ws_size - 16384) & ~(size_t)1023;
  bf16* ewsB = (bf16*)((char*)d_ws + hdr);
  float* S4f = (float*)((char*)d_ws + hdr + 12288);
  precompute_tables<<<1, 256, 0, stream>>>(eqh, eqw, ekh, ekw, evh, evw, ewsB, S4f);

  if (ws_size >= (size_t)73 * 1024 * 1024) {
    // -------- full-batch path: ws = q(32M) | k(32M) | weights(8M) --------
    bf16* qb = (bf16*)d_ws;
    bf16* kb = qb + 16777216;
    bf16* wqb = kb + 16777216;
    bf16* wkb = wqb + 1048576;
    bf16* wvb = wkb + 1048576;
    bf16* wob = wvb + 1048576;
    bf16* xb = (bf16*)d_out;                      // d_out[0,32M): x bf16 (dead after QKV gemm)
    bf16* vb = (bf16*)((char*)d_out + 33554432);  // d_out[32M,64M): v (dead after attn)

    convert_f32_bf16<<<8192, 256, 0, stream>>>(x, xb, 16777216);
    convert_f32_bf16<<<512, 256, 0, stream>>>(wq, wqb, 1048576);
    convert_f32_bf16<<<512, 256, 0, stream>>>(wk, wkb, 1048576);
    convert_f32_bf16<<<512, 256, 0, stream>>>(wv, wvb, 1048576);
    convert_f32_bf16<<<512, 256, 0, stream>>>(wo, wob, 1048576);

    gemm_bt<0><<<dim3(128, 24), 256, 0, stream>>>(
        xb, wqb, wkb, wvb, 1, nullptr, 0, qb, kb, vb, nullptr, 0);
    attn_rel<<<dim3(4096), 256, 0, stream>>>(qb, kb, vb, ewsB, S4f, qb);
    gemm_bt<1><<<dim3(128, 8), 256, 0, stream>>>(
        qb, wob, nullptr, nullptr, 1, bo, 1, nullptr, nullptr, nullptr, outf, 1);
  } else {
    // -------- halved path --------
    bf16* xb0 = (bf16*)((char*)d_out + 16777216);   // Q1
    bf16* xb1 = (bf16*)((char*)d_out + 50331648);   // Q3
    bf16* vQ2 = (bf16*)((char*)d_out + 33554432);   // Q2
    bf16* qb = (bf16*)d_ws;
    bf16* kb = qb + 8388608;
    const int fastW = (ws_size >= (size_t)42 * 1024 * 1024) ? 1 : 0;
    bf16* wqb = kb + 8388608;
    bf16* wkb = wqb + 1048576;
    bf16* wvb = wkb + 1048576;
    bf16* wob = wvb + 1048576;

    convert_f32_bf16<<<4096, 256, 0, stream>>>(x, xb0, 8388608);
    convert_f32_bf16<<<4096, 256, 0, stream>>>(x + 8388608, xb1, 8388608);
    if (fastW) {
      convert_f32_bf16<<<512, 256, 0, stream>>>(wq, wqb, 1048576);
      convert_f32_bf16<<<512, 256, 0, stream>>>(wk, wkb, 1048576);
      convert_f32_bf16<<<512, 256, 0, stream>>>(wv, wvb, 1048576);
      convert_f32_bf16<<<512, 256, 0, stream>>>(wo, wob, 1048576);
    }

    for (int hh = 0; hh < 2; ++hh) {
      const bf16* xh = hh ? xb1 : xb0;
      gemm_bt<0><<<dim3(64, 24), 256, 0, stream>>>(
          xh,
          fastW ? (const void*)wqb : (const void*)wq,
          fastW ? (const void*)wkb : (const void*)wk,
          fastW ? (const void*)wvb : (const void*)wv,
          fastW, nullptr, 0, qb, kb, vQ2, nullptr, 0);
      attn_rel<<<dim3(2048), 256, 0, stream>>>(qb, kb, vQ2, ewsB, S4f, qb);
      gemm_bt<1><<<dim3(64, 8), 256, 0, stream>>>(
          qb,
          fastW ? (const void*)wob : (const void*)wo, nullptr, nullptr,
          fastW, bo, 1, nullptr, nullptr, nullptr,
          outf + (size_t)hh * 8388608, 1);
    }
  }
}